// Round 9
// baseline (1939.956 us; speedup 1.0000x reference)
//
#include <hip/hip_runtime.h>
#include <hip/hip_bf16.h>
#include <math.h>

#define H_DIM 2048
#define N_ST 8
#define B_SZ 4
#define L_SEQ 4096
#define DMODEL 1024
#define DCONV 4
#define CL 128
#define NC (L_SEQ / CL)   // 32

typedef __bf16 bf16x8 __attribute__((ext_vector_type(8)));
typedef __bf16 bf16x4 __attribute__((ext_vector_type(4)));
typedef float f32x4 __attribute__((ext_vector_type(4)));

typedef const unsigned int __attribute__((address_space(1)))* gptr_t;
typedef unsigned int __attribute__((address_space(3)))* lptr_t;

__device__ __forceinline__ void gl_lds16(const __bf16* g, __bf16* l) {
    __builtin_amdgcn_global_load_lds((gptr_t)g, (lptr_t)l, 16, 0, 0);
}

// -------- workspace layout (floats), total ~32.9M f = 131.5 MB --------
#define WS_XZ     0
#define WS_YTH    8388608
#define WS_YTL    12582912
#define WS_COEF   16777216
#define WS_STATES 16875520
#define WS_LOOK   17924096
#define WS_HF     18186240   // fused hid  bf16 [4096][3072]
#define WS_WIF    24477696   // fused W_in bf16 [4096][3072]
#define WS_WOH    30769152   // W_out hi plane bf16 [1024][2048]
#define WS_WOL    31817728   // W_out lo plane

// ============ split f32 -> bf16 hi/lo planes (for W_out) ============
__global__ __launch_bounds__(256) void cvt_split4(const float* __restrict__ s,
                                                  __bf16* __restrict__ h,
                                                  __bf16* __restrict__ l, int n4) {
    int i = blockIdx.x * 256 + threadIdx.x;
    if (i >= n4) return;
    float4 v = ((const float4*)s)[i];
    float vv[4] = {v.x, v.y, v.z, v.w};
    bf16x4 hv, lv;
#pragma unroll
    for (int j = 0; j < 4; ++j) {
        __bf16 hb = (__bf16)vv[j];
        hv[j] = hb;
        lv[j] = (__bf16)(vv[j] - (float)hb);
    }
    *(bf16x4*)&h[(size_t)i * 4] = hv;
    *(bf16x4*)&l[(size_t)i * 4] = lv;
}

// ============ fuse f32 [R][1024] -> bf16 [R][3072] triplet octs ============
// A-side: [h][h][l]; B-side: [h][l][h]  =>  sum = AhBh + AhBl + AlBh.
template <int BSIDE>
__global__ __launch_bounds__(256) void cvt_fuse(const float* __restrict__ s,
                                                __bf16* __restrict__ d, int nOct) {
    int i = blockIdx.x * 256 + threadIdx.x;
    if (i >= nOct) return;
    int row = i >> 7, ko = i & 127;          // K=1024 -> 128 octs/row
    const float* p = s + (size_t)row * 1024 + ko * 8;
    float4 v0 = *(const float4*)p;
    float4 v1 = *(const float4*)(p + 4);
    float vv[8] = {v0.x, v0.y, v0.z, v0.w, v1.x, v1.y, v1.z, v1.w};
    bf16x8 hv, lv;
#pragma unroll
    for (int j = 0; j < 8; ++j) {
        __bf16 hb = (__bf16)vv[j];
        hv[j] = hb;
        lv[j] = (__bf16)(vv[j] - (float)hb);
    }
    __bf16* o = d + (size_t)row * 3072 + ko * 24;
    if (BSIDE) {
        *(bf16x8*)(o) = hv; *(bf16x8*)(o + 8) = lv; *(bf16x8*)(o + 16) = hv;
    } else {
        *(bf16x8*)(o) = hv; *(bf16x8*)(o + 8) = hv; *(bf16x8*)(o + 16) = lv;
    }
}

// ============ coefficient precompute ============
__global__ void coef_kernel(const float* __restrict__ log_dt,
                            const float* __restrict__ log_A_real,
                            const float* __restrict__ A_imag,
                            const float* __restrict__ C_re,
                            const float* __restrict__ C_im,
                            float* __restrict__ coef) {
    int i = blockIdx.x * blockDim.x + threadIdx.x;
    if (i >= H_DIM * N_ST) return;
    int h = i >> 3;
    float dt = expf(log_dt[h]);
    float Ar = -expf(log_A_real[i]);
    float Ai = A_imag[i];
    float er = expf(dt * Ar);
    float ang = dt * Ai;
    float wr = er * cosf(ang);
    float wi = er * sinf(ang);
    float den = Ar * Ar + Ai * Ai;
    float qr = ((wr - 1.f) * Ar + wi * Ai) / den;
    float qi = (wi * Ar - (wr - 1.f) * Ai) / den;
    float Cr = C_re[i], Ci = C_im[i];
    float Ctr = Cr * qr - Ci * qi;
    float Cti = Cr * qi + Ci * qr;
    float eCL = expf((float)CL * dt * Ar);
    float aCL = (float)CL * dt * Ai;
    float pr = eCL * cosf(aCL);
    float pi = eCL * sinf(aCL);
    const int HN = H_DIM * N_ST;
    coef[i]          = wr;
    coef[HN + i]     = wi;
    coef[2 * HN + i] = Ctr;
    coef[3 * HN + i] = Cti;
    coef[4 * HN + i] = pr;
    coef[5 * HN + i] = pi;
}

// ============ m97-faithful fused bf16 GEMM: 128x128 tile, single-buffer, plain ============
// C[M][N] = sum_k' A[m][k']*B[n][k'] over fused K'. 4 waves (2x2), wave tile 64x64,
// BK=32, 16 KiB LDS single-buffered, __syncthreads only, no inline asm.
// High blocks/CU co-residency does the latency hiding (m97 mechanism).
__global__ __launch_bounds__(256) void gemm_f128(const __bf16* __restrict__ A,
                                                 const __bf16* __restrict__ B,
                                                 float* __restrict__ C,
                                                 int K, int ldc) {
    __shared__ __bf16 sA[4096], sB[4096];   // [kb4][row128][8]
    const int tid = threadIdx.x;
    const int lane = tid & 63;
    const int wid = tid >> 6;
    const int wrw = wid >> 1, wcw = wid & 1;
    const int bm = blockIdx.y, bn = blockIdx.x;

    // staging map: oct o = q*256 + tid -> kb = o>>7, row = o&127, dst elem o*8
    const int o0 = tid, o1 = 256 + tid;
    const int kbA0 = o0 >> 7, rowA0 = o0 & 127;
    const int kbA1 = o1 >> 7, rowA1 = o1 & 127;
    const size_t arow0 = (size_t)(bm * 128 + rowA0) * K;
    const size_t arow1 = (size_t)(bm * 128 + rowA1) * K;
    const size_t brow0 = (size_t)(bn * 128 + rowA0) * K;
    const size_t brow1 = (size_t)(bn * 128 + rowA1) * K;

    f32x4 acc[4][4];
#pragma unroll
    for (int m = 0; m < 4; ++m)
#pragma unroll
        for (int n = 0; n < 4; ++n) acc[m][n] = (f32x4){0.f, 0.f, 0.f, 0.f};

    const int kb = lane >> 4, rr = lane & 15;
    const int offA0 = kb * 1024 + (wrw * 64 + rr) * 8;   // + m*128
    const int offB0 = kb * 1024 + (wcw * 64 + rr) * 8;   // + n*128

    for (int kt = 0; kt < K; kt += 32) {
        __syncthreads();
        gl_lds16(A + arow0 + kt + kbA0 * 8, &sA[o0 * 8]);
        gl_lds16(A + arow1 + kt + kbA1 * 8, &sA[o1 * 8]);
        gl_lds16(B + brow0 + kt + kbA0 * 8, &sB[o0 * 8]);
        gl_lds16(B + brow1 + kt + kbA1 * 8, &sB[o1 * 8]);
        __syncthreads();

        bf16x8 fA[4], fB[4];
#pragma unroll
        for (int m = 0; m < 4; ++m) fA[m] = *(const bf16x8*)&sA[offA0 + m * 128];
#pragma unroll
        for (int n = 0; n < 4; ++n) fB[n] = *(const bf16x8*)&sB[offB0 + n * 128];
#pragma unroll
        for (int m = 0; m < 4; ++m)
#pragma unroll
            for (int n = 0; n < 4; ++n)
                acc[m][n] = __builtin_amdgcn_mfma_f32_16x16x32_bf16(fA[m], fB[n], acc[m][n], 0, 0, 0);
    }

    const int rq = lane >> 4;
#pragma unroll
    for (int m = 0; m < 4; ++m)
#pragma unroll
        for (int n = 0; n < 4; ++n) {
            int col = bn * 128 + wcw * 64 + n * 16 + rr;
            int row0 = bm * 128 + wrw * 64 + m * 16 + rq * 4;
#pragma unroll
            for (int j = 0; j < 4; ++j)
                C[(size_t)(row0 + j) * ldc + col] = acc[m][n][j];
        }
}

// ============ 128x128 split-bf16 MFMA GEMM (out_proj; depth-2 prefetch) ============
__global__ __launch_bounds__(256, 2) void gemm_split(const __bf16* __restrict__ Ah,
                                                     const __bf16* __restrict__ Al,
                                                     const __bf16* __restrict__ Bh,
                                                     const __bf16* __restrict__ Bl,
                                                     float* __restrict__ C,
                                                     int K, int ldc) {
    __shared__ __bf16 sAh[2][4096], sAl[2][4096], sBh[2][4096], sBl[2][4096];
    const int tid = threadIdx.x;
    const int lane = tid & 63;
    const int wid = tid >> 6;
    const int wrw = wid >> 1, wcw = wid & 1;
    const int bm = blockIdx.y, bn = blockIdx.x;

    const int r = tid & 127;
    const int kbq8 = (tid >> 7) * 8;
    const size_t arow = (size_t)(bm * 128 + r) * K;
    const size_t brow = (size_t)(bn * 128 + r) * K;

    f32x4 acc[4][4];
#pragma unroll
    for (int m = 0; m < 4; ++m)
#pragma unroll
        for (int n = 0; n < 4; ++n) acc[m][n] = (f32x4){0.f, 0.f, 0.f, 0.f};

    const int kb = lane >> 4, rr = lane & 15;

    auto stage = [&](int b, int k0) {
#pragma unroll
        for (int q = 0; q < 2; ++q) {
            const int lo = q * 2048 + tid * 8;
            const size_t go = (size_t)k0 + q * 16 + kbq8;
            gl_lds16(Ah + arow + go, &sAh[b][lo]);
            gl_lds16(Al + arow + go, &sAl[b][lo]);
            gl_lds16(Bh + brow + go, &sBh[b][lo]);
            gl_lds16(Bl + brow + go, &sBl[b][lo]);
        }
    };

    const int nt = K >> 5;
    stage(0, 0);
    stage(1, 32);
    asm volatile("s_waitcnt vmcnt(8)" ::: "memory");
    __builtin_amdgcn_s_barrier();

    for (int t = 0; t < nt; ++t) {
        const int cur = t & 1;
        bf16x8 fAh[4], fAl[4], fBh[4], fBl[4];
#pragma unroll
        for (int m = 0; m < 4; ++m) {
            int off = kb * 1024 + (wrw * 64 + m * 16 + rr) * 8;
            fAh[m] = *(const bf16x8*)&sAh[cur][off];
            fAl[m] = *(const bf16x8*)&sAl[cur][off];
        }
#pragma unroll
        for (int n = 0; n < 4; ++n) {
            int off = kb * 1024 + (wcw * 64 + n * 16 + rr) * 8;
            fBh[n] = *(const bf16x8*)&sBh[cur][off];
            fBl[n] = *(const bf16x8*)&sBl[cur][off];
        }
        asm volatile("s_waitcnt lgkmcnt(0)" ::: "memory");
        __builtin_amdgcn_sched_barrier(0);
        __builtin_amdgcn_s_barrier();
        __builtin_amdgcn_sched_barrier(0);
        if (t + 2 < nt) stage(cur, (t + 2) << 5);
        __builtin_amdgcn_s_setprio(1);
#pragma unroll
        for (int m = 0; m < 4; ++m)
#pragma unroll
            for (int n = 0; n < 4; ++n) {
                acc[m][n] = __builtin_amdgcn_mfma_f32_16x16x32_bf16(fAh[m], fBh[n], acc[m][n], 0, 0, 0);
                acc[m][n] = __builtin_amdgcn_mfma_f32_16x16x32_bf16(fAh[m], fBl[n], acc[m][n], 0, 0, 0);
                acc[m][n] = __builtin_amdgcn_mfma_f32_16x16x32_bf16(fAl[m], fBh[n], acc[m][n], 0, 0, 0);
            }
        __builtin_amdgcn_s_setprio(0);
        if (t + 2 < nt) asm volatile("s_waitcnt vmcnt(8)" ::: "memory");
        else            asm volatile("s_waitcnt vmcnt(0)" ::: "memory");
        __builtin_amdgcn_s_barrier();
    }

    const int rq = lane >> 4;
#pragma unroll
    for (int m = 0; m < 4; ++m)
#pragma unroll
        for (int n = 0; n < 4; ++n) {
            int col = bn * 128 + wcw * 64 + n * 16 + rr;
            int row0 = bm * 128 + wrw * 64 + m * 16 + rq * 4;
#pragma unroll
            for (int j = 0; j < 4; ++j)
                C[(size_t)(row0 + j) * ldc + col] = acc[m][n][j];
        }
}

// ============ scan phase 1: local chunk scans (fused conv+SiLU) ============
__global__ __launch_bounds__(256) void scan_phase1(const float* __restrict__ xz,
                                                   const float* __restrict__ coef,
                                                   const float* __restrict__ conv_w,
                                                   const float* __restrict__ conv_b,
                                                   float* __restrict__ states,
                                                   float* __restrict__ look) {
    int t = blockIdx.x * 256 + threadIdx.x;   // t = h*NC + c
    int c = t & (NC - 1);
    int h = t >> 5;

    const int HN = H_DIM * N_ST;
    float wr[N_ST], wi[N_ST];
#pragma unroll
    for (int n = 0; n < N_ST; ++n) {
        wr[n] = coef[h * N_ST + n];
        wi[n] = coef[HN + h * N_ST + n];
    }
    float cw0 = conv_w[h * 4 + 0], cw1 = conv_w[h * 4 + 1];
    float cw2 = conv_w[h * 4 + 2], cw3 = conv_w[h * 4 + 3];
    float cb = conv_b[h];

    const float* xrow = xz + (size_t)h * L_SEQ + c * CL;
    float x3 = 0.f, x2 = 0.f, x1 = 0.f;
    if (c > 0) {
        float4 p = *(const float4*)(xrow - 4);
        x3 = p.y; x2 = p.z; x1 = p.w;
    }
    *(float4*)(look + (size_t)t * 4) = make_float4(x3, x2, x1, 0.f);

    float sr[N_ST], si[N_ST];
#pragma unroll
    for (int n = 0; n < N_ST; ++n) { sr[n] = 0.f; si[n] = 0.f; }

    for (int j = 0; j < CL; j += 4) {
        float4 v = *(const float4*)(xrow + j);
        float xv[4] = {v.x, v.y, v.z, v.w};
#pragma unroll
        for (int k = 0; k < 4; ++k) {
            float u = cw0 * x3 + cw1 * x2 + cw2 * x1 + cw3 * xv[k] + cb;
            float xc = u / (1.f + __expf(-u));
            x3 = x2; x2 = x1; x1 = xv[k];
#pragma unroll
            for (int n = 0; n < N_ST; ++n) {
                float nr = wr[n] * sr[n] - wi[n] * si[n] + xc;
                float ni = wr[n] * si[n] + wi[n] * sr[n];
                sr[n] = nr; si[n] = ni;
            }
        }
    }
    float* st = states + (size_t)t * (N_ST * 2);
#pragma unroll
    for (int n = 0; n < N_ST; ++n) { st[2 * n] = sr[n]; st[2 * n + 1] = si[n]; }
}

// ============ scan phase 2: combine chunk states -> chunk init states ============
__global__ __launch_bounds__(256) void scan_phase2(const float* __restrict__ coef,
                                                   float* __restrict__ states) {
    int h = blockIdx.x * 256 + threadIdx.x;
    if (h >= H_DIM) return;
    const int HN = H_DIM * N_ST;
    float pr[N_ST], pi[N_ST];
#pragma unroll
    for (int n = 0; n < N_ST; ++n) {
        pr[n] = coef[4 * HN + h * N_ST + n];
        pi[n] = coef[5 * HN + h * N_ST + n];
    }
    float sr[N_ST], si[N_ST];
#pragma unroll
    for (int n = 0; n < N_ST; ++n) { sr[n] = 0.f; si[n] = 0.f; }
    float* base = states + (size_t)h * NC * (N_ST * 2);
    for (int c = 0; c < NC; ++c) {
        float* st = base + c * (N_ST * 2);
#pragma unroll
        for (int n = 0; n < N_ST; ++n) {
            float lr = st[2 * n], li = st[2 * n + 1];
            st[2 * n] = sr[n]; st[2 * n + 1] = si[n];
            float nr = pr[n] * sr[n] - pi[n] * si[n] + lr;
            float ni = pr[n] * si[n] + pi[n] * sr[n] + li;
            sr[n] = nr; si[n] = ni;
        }
    }
}

// ============ scan phase 3: replay, fused D-skip + gate; writes y f32 OVER x ============
__global__ __launch_bounds__(256) void scan_phase3(float* __restrict__ xz,
                                                   const float* __restrict__ coef,
                                                   const float* __restrict__ conv_w,
                                                   const float* __restrict__ conv_b,
                                                   const float* __restrict__ Dvec,
                                                   const float* __restrict__ states,
                                                   const float* __restrict__ look) {
    int t = blockIdx.x * 256 + threadIdx.x;
    int c = t & (NC - 1);
    int h = t >> 5;

    const int HN = H_DIM * N_ST;
    float wr[N_ST], wi[N_ST], Ctr[N_ST], Cti[N_ST];
#pragma unroll
    for (int n = 0; n < N_ST; ++n) {
        wr[n]  = coef[h * N_ST + n];
        wi[n]  = coef[HN + h * N_ST + n];
        Ctr[n] = coef[2 * HN + h * N_ST + n];
        Cti[n] = coef[3 * HN + h * N_ST + n];
    }
    float cw0 = conv_w[h * 4 + 0], cw1 = conv_w[h * 4 + 1];
    float cw2 = conv_w[h * 4 + 2], cw3 = conv_w[h * 4 + 3];
    float cb = conv_b[h];
    float Dh = Dvec[h];

    float* xrow = xz + (size_t)h * L_SEQ + c * CL;
    const float* zrow = xz + (size_t)(H_DIM + h) * L_SEQ + c * CL;

    float4 lk = *(const float4*)(look + (size_t)t * 4);
    float x3 = lk.x, x2 = lk.y, x1 = lk.z;

    const float* st = states + (size_t)t * (N_ST * 2);
    float sr[N_ST], si[N_ST];
#pragma unroll
    for (int n = 0; n < N_ST; ++n) { sr[n] = st[2 * n]; si[n] = st[2 * n + 1]; }

    for (int j = 0; j < CL; j += 4) {
        float4 v = *(const float4*)(xrow + j);
        float4 zv = *(const float4*)(zrow + j);
        float xv[4] = {v.x, v.y, v.z, v.w};
        float zz[4] = {zv.x, zv.y, zv.z, zv.w};
        float out[4];
#pragma unroll
        for (int k = 0; k < 4; ++k) {
            float u = cw0 * x3 + cw1 * x2 + cw2 * x1 + cw3 * xv[k] + cb;
            float xc = u / (1.f + __expf(-u));
            x3 = x2; x2 = x1; x1 = xv[k];
            float accy = 0.f;
#pragma unroll
            for (int n = 0; n < N_ST; ++n) {
                float nr = wr[n] * sr[n] - wi[n] * si[n] + xc;
                float ni = wr[n] * si[n] + wi[n] * sr[n];
                sr[n] = nr; si[n] = ni;
                accy += Ctr[n] * nr - Cti[n] * ni;
            }
            float yv = 2.f * accy + Dh * xc;
            float g = zz[k] / (1.f + __expf(-zz[k]));
            out[k] = yv * g;
        }
        *(float4*)(xrow + j) = make_float4(out[0], out[1], out[2], out[3]);
    }
}

// ============ transpose + split: y f32 [H][L] -> yTh/yTl bf16 [L][H] ============
__global__ __launch_bounds__(256) void transpose_split(const float* __restrict__ y,
                                                       __bf16* __restrict__ th,
                                                       __bf16* __restrict__ tl) {
    __shared__ float tile[64][65];
    const int l0 = blockIdx.x * 64, h0 = blockIdx.y * 64;
    const int tid = threadIdx.x;
    const int r = tid >> 4, c4 = (tid & 15) * 4;
#pragma unroll
    for (int p = 0; p < 4; ++p) {
        float4 v = *(const float4*)(y + (size_t)(h0 + r + p * 16) * L_SEQ + l0 + c4);
        tile[r + p * 16][c4 + 0] = v.x;
        tile[r + p * 16][c4 + 1] = v.y;
        tile[r + p * 16][c4 + 2] = v.z;
        tile[r + p * 16][c4 + 3] = v.w;
    }
    __syncthreads();
    const int l = tid >> 2, hb = (tid & 3) * 16;
    float vals[16];
#pragma unroll
    for (int j = 0; j < 16; ++j) vals[j] = tile[hb + j][l];
    bf16x8 hv0, hv1, lv0, lv1;
#pragma unroll
    for (int j = 0; j < 8; ++j) {
        __bf16 hbv = (__bf16)vals[j];
        hv0[j] = hbv;
        lv0[j] = (__bf16)(vals[j] - (float)hbv);
        __bf16 hbv2 = (__bf16)vals[j + 8];
        hv1[j] = hbv2;
        lv1[j] = (__bf16)(vals[j + 8] - (float)hbv2);
    }
    size_t base = (size_t)(l0 + l) * H_DIM + h0 + hb;
    *(bf16x8*)&th[base] = hv0;
    *(bf16x8*)&th[base + 8] = hv1;
    *(bf16x8*)&tl[base] = lv0;
    *(bf16x8*)&tl[base + 8] = lv1;
}

extern "C" void kernel_launch(void* const* d_in, const int* in_sizes, int n_in,
                              void* d_out, int out_size, void* d_ws, size_t ws_size,
                              hipStream_t stream) {
    const float* hid        = (const float*)d_in[0];
    const float* W_in       = (const float*)d_in[1];
    const float* conv_w     = (const float*)d_in[2];
    const float* conv_b     = (const float*)d_in[3];
    const float* log_dt     = (const float*)d_in[4];
    const float* log_A_real = (const float*)d_in[5];
    const float* A_imag     = (const float*)d_in[6];
    const float* C_re       = (const float*)d_in[7];
    const float* C_im       = (const float*)d_in[8];
    const float* Dv         = (const float*)d_in[9];
    const float* W_out      = (const float*)d_in[10];
    float* out = (float*)d_out;
    float* ws  = (float*)d_ws;

    float* xz      = ws + WS_XZ;
    __bf16* yTh    = (__bf16*)(ws + WS_YTH);
    __bf16* yTl    = (__bf16*)(ws + WS_YTL);
    float* coef    = ws + WS_COEF;
    float* states  = ws + WS_STATES;
    float* look    = ws + WS_LOOK;
    __bf16* Hf     = (__bf16*)(ws + WS_HF);
    __bf16* WiF    = (__bf16*)(ws + WS_WIF);
    __bf16* Woh    = (__bf16*)(ws + WS_WOH);
    __bf16* Wol    = (__bf16*)(ws + WS_WOL);

    coef_kernel<<<(H_DIM * N_ST + 255) / 256, 256, 0, stream>>>(
        log_dt, log_A_real, A_imag, C_re, C_im, coef);

    const int wOct = 2 * H_DIM * DMODEL / 8;   // 524288
    cvt_fuse<0><<<(wOct + 255) / 256, 256, 0, stream>>>(W_in, WiF, wOct);
    cvt_split4<<<(DMODEL * H_DIM / 4 + 255) / 256, 256, 0, stream>>>(W_out, Woh, Wol, DMODEL * H_DIM / 4);

    const int nscan = H_DIM * NC;              // 65536
    const int hOct = L_SEQ * DMODEL / 8;       // 524288
    dim3 gIn(L_SEQ / 128, 2 * H_DIM / 128);    // (32,32) = 1024 blocks
    dim3 gOut(DMODEL / 128, L_SEQ / 128);      // (8,32)  = 256 blocks
    dim3 gTr(L_SEQ / 64, H_DIM / 64);          // (64,32)

    for (int b = 0; b < B_SZ; ++b) {
        const float* hid_b = hid + (size_t)b * L_SEQ * DMODEL;
        float* out_b = out + (size_t)b * L_SEQ * DMODEL;

        cvt_fuse<1><<<(hOct + 255) / 256, 256, 0, stream>>>(hid_b, Hf, hOct);
        gemm_f128<<<gIn, 256, 0, stream>>>(WiF, Hf, xz, 3 * DMODEL, L_SEQ);
        scan_phase1<<<nscan / 256, 256, 0, stream>>>(xz, coef, conv_w, conv_b, states, look);
        scan_phase2<<<(H_DIM + 255) / 256, 256, 0, stream>>>(coef, states);
        scan_phase3<<<nscan / 256, 256, 0, stream>>>(xz, coef, conv_w, conv_b, Dv, states, look);
        transpose_split<<<gTr, 256, 0, stream>>>(xz, yTh, yTl);
        gemm_split<<<gOut, 256, 0, stream>>>(yTh, yTl, Woh, Wol, out_b, H_DIM, DMODEL);
    }
}

// Round 10
// 1510.755 us; speedup vs baseline: 1.2841x; 1.2841x over previous
//
#include <hip/hip_runtime.h>
#include <hip/hip_bf16.h>
#include <math.h>

#define H_DIM 2048
#define N_ST 8
#define B_SZ 4
#define L_SEQ 4096
#define DMODEL 1024
#define DCONV 4
#define CL 128
#define NC (L_SEQ / CL)   // 32

typedef __bf16 bf16x8 __attribute__((ext_vector_type(8)));
typedef __bf16 bf16x4 __attribute__((ext_vector_type(4)));
typedef float f32x4 __attribute__((ext_vector_type(4)));

typedef const unsigned int __attribute__((address_space(1)))* gptr_t;
typedef unsigned int __attribute__((address_space(3)))* lptr_t;

__device__ __forceinline__ void gl_lds16(const __bf16* g, __bf16* l) {
    __builtin_amdgcn_global_load_lds((gptr_t)g, (lptr_t)l, 16, 0, 0);
}

// -------- workspace layout (floats), total ~32.9M f = 131.5 MB --------
#define WS_XZ     0
#define WS_YTH    8388608
#define WS_YTL    12582912
#define WS_COEF   16777216
#define WS_STATES 16875520
#define WS_LOOK   17924096
#define WS_HF     18186240   // fused hid  bf16 [4096][3072]
#define WS_WIF    24477696   // fused W_in bf16 [4096][3072]
#define WS_WOH    30769152   // W_out hi plane bf16 [1024][2048]
#define WS_WOL    31817728   // W_out lo plane

// ============ split f32 -> bf16 hi/lo planes (for W_out) ============
__global__ __launch_bounds__(256) void cvt_split4(const float* __restrict__ s,
                                                  __bf16* __restrict__ h,
                                                  __bf16* __restrict__ l, int n4) {
    int i = blockIdx.x * 256 + threadIdx.x;
    if (i >= n4) return;
    float4 v = ((const float4*)s)[i];
    float vv[4] = {v.x, v.y, v.z, v.w};
    bf16x4 hv, lv;
#pragma unroll
    for (int j = 0; j < 4; ++j) {
        __bf16 hb = (__bf16)vv[j];
        hv[j] = hb;
        lv[j] = (__bf16)(vv[j] - (float)hb);
    }
    *(bf16x4*)&h[(size_t)i * 4] = hv;
    *(bf16x4*)&l[(size_t)i * 4] = lv;
}

// ============ fuse f32 [R][1024] -> bf16 [R][3072] triplet octs ============
// A-side: [h][h][l]; B-side: [h][l][h]  =>  sum = AhBh + AhBl + AlBh.
template <int BSIDE>
__global__ __launch_bounds__(256) void cvt_fuse(const float* __restrict__ s,
                                                __bf16* __restrict__ d, int nOct) {
    int i = blockIdx.x * 256 + threadIdx.x;
    if (i >= nOct) return;
    int row = i >> 7, ko = i & 127;          // K=1024 -> 128 octs/row
    const float* p = s + (size_t)row * 1024 + ko * 8;
    float4 v0 = *(const float4*)p;
    float4 v1 = *(const float4*)(p + 4);
    float vv[8] = {v0.x, v0.y, v0.z, v0.w, v1.x, v1.y, v1.z, v1.w};
    bf16x8 hv, lv;
#pragma unroll
    for (int j = 0; j < 8; ++j) {
        __bf16 hb = (__bf16)vv[j];
        hv[j] = hb;
        lv[j] = (__bf16)(vv[j] - (float)hb);
    }
    __bf16* o = d + (size_t)row * 3072 + ko * 24;
    if (BSIDE) {
        *(bf16x8*)(o) = hv; *(bf16x8*)(o + 8) = lv; *(bf16x8*)(o + 16) = hv;
    } else {
        *(bf16x8*)(o) = hv; *(bf16x8*)(o + 8) = hv; *(bf16x8*)(o + 16) = lv;
    }
}

// ============ coefficient precompute ============
__global__ void coef_kernel(const float* __restrict__ log_dt,
                            const float* __restrict__ log_A_real,
                            const float* __restrict__ A_imag,
                            const float* __restrict__ C_re,
                            const float* __restrict__ C_im,
                            float* __restrict__ coef) {
    int i = blockIdx.x * blockDim.x + threadIdx.x;
    if (i >= H_DIM * N_ST) return;
    int h = i >> 3;
    float dt = expf(log_dt[h]);
    float Ar = -expf(log_A_real[i]);
    float Ai = A_imag[i];
    float er = expf(dt * Ar);
    float ang = dt * Ai;
    float wr = er * cosf(ang);
    float wi = er * sinf(ang);
    float den = Ar * Ar + Ai * Ai;
    float qr = ((wr - 1.f) * Ar + wi * Ai) / den;
    float qi = (wi * Ar - (wr - 1.f) * Ai) / den;
    float Cr = C_re[i], Ci = C_im[i];
    float Ctr = Cr * qr - Ci * qi;
    float Cti = Cr * qi + Ci * qr;
    float eCL = expf((float)CL * dt * Ar);
    float aCL = (float)CL * dt * Ai;
    float pr = eCL * cosf(aCL);
    float pi = eCL * sinf(aCL);
    const int HN = H_DIM * N_ST;
    coef[i]          = wr;
    coef[HN + i]     = wi;
    coef[2 * HN + i] = Ctr;
    coef[3 * HN + i] = Cti;
    coef[4 * HN + i] = pr;
    coef[5 * HN + i] = pi;
}

// ============ 256x256 fused bf16 GEMM — faithful 4-phase/K-half schedule ============
// Slots: (tile-parity, ks) x {A,B}; per phase: {ds_read frags | stage 1 piece (2 gl_lds)
//  | barrier | lgkm(0) | setprio 16 MFMA | [vmcnt(4) at ph1/ph3] | barrier}.
// Steady state keeps 4 loads in flight; vmcnt never drains except final iter.
__global__ __launch_bounds__(512, 2) void gemm_f256p(const __bf16* __restrict__ A,
                                                     const __bf16* __restrict__ B,
                                                     float* __restrict__ C,
                                                     int K, int ldc) {
    __shared__ __bf16 sA[32768], sB[32768];   // [par][ks][kb][256 rows][8] each
    const int tid = threadIdx.x;
    const int lane = tid & 63;
    const int wid = tid >> 6;
    const int wrw = wid >> 2, wcw = wid & 3;
    const int bm = blockIdx.y, bn = blockIdx.x;

    f32x4 acc[8][4];
#pragma unroll
    for (int m = 0; m < 8; ++m)
#pragma unroll
        for (int n = 0; n < 4; ++n) acc[m][n] = (f32x4){0.f, 0.f, 0.f, 0.f};

    const int kb = lane >> 4, rr = lane & 15;

    // staging line constants (2 lines per piece)
    const int f0 = tid, f1 = 512 + tid;
    const int kA0 = f0 >> 8, rA0 = f0 & 255;
    const int kA1 = f1 >> 8, rA1 = f1 & 255;
    const size_t gA0 = (size_t)(bm * 256 + rA0) * K;
    const size_t gA1 = (size_t)(bm * 256 + rA1) * K;
    const size_t gB0 = (size_t)(bn * 256 + rA0) * K;
    const size_t gB1 = (size_t)(bn * 256 + rA1) * K;
    const int dst0 = kA0 * 2048 + rA0 * 8;
    const int dst1 = kA1 * 2048 + rA1 * 8;

    auto stageA = [&](int t, int ks) {
        const int base = (t & 1) * 16384 + ks * 8192;
        const size_t go = (size_t)t * 64 + ks * 32;
        gl_lds16(A + gA0 + go + kA0 * 8, &sA[base + dst0]);
        gl_lds16(A + gA1 + go + kA1 * 8, &sA[base + dst1]);
    };
    auto stageB = [&](int t, int ks) {
        const int base = (t & 1) * 16384 + ks * 8192;
        const size_t go = (size_t)t * 64 + ks * 32;
        gl_lds16(B + gB0 + go + kA0 * 8, &sB[base + dst0]);
        gl_lds16(B + gB1 + go + kA1 * 8, &sB[base + dst1]);
    };

    const int nt = K >> 6;   // BK=64
    // prologue: tile 0 fully resident
    stageA(0, 0); stageB(0, 0); stageA(0, 1); stageB(0, 1);
    asm volatile("s_waitcnt vmcnt(0)" ::: "memory");
    __builtin_amdgcn_s_barrier();
    __builtin_amdgcn_sched_barrier(0);

#pragma unroll 1
    for (int t = 0; t < nt; ++t) {
        const int par = (t & 1) * 16384;
        const bool pf = (t + 1 < nt);
        bf16x8 fB[4], fA[4];

        // ===== phase 0: (mh=0, ks=0) =====
        {
            const int bA = par, bB = par;
#pragma unroll
            for (int n = 0; n < 4; ++n)
                fB[n] = *(const bf16x8*)&sB[bB + kb * 2048 + (wcw * 64 + n * 16 + rr) * 8];
#pragma unroll
            for (int m = 0; m < 4; ++m)
                fA[m] = *(const bf16x8*)&sA[bA + kb * 2048 + (wrw * 128 + m * 16 + rr) * 8];
            if (pf) stageA(t + 1, 0);
            __builtin_amdgcn_s_barrier();
            asm volatile("s_waitcnt lgkmcnt(0)" ::: "memory");
            __builtin_amdgcn_sched_barrier(0);
            __builtin_amdgcn_s_setprio(1);
#pragma unroll
            for (int m = 0; m < 4; ++m)
#pragma unroll
                for (int n = 0; n < 4; ++n)
                    acc[m][n] = __builtin_amdgcn_mfma_f32_16x16x32_bf16(fA[m], fB[n], acc[m][n], 0, 0, 0);
            __builtin_amdgcn_s_setprio(0);
            __builtin_amdgcn_s_barrier();
            __builtin_amdgcn_sched_barrier(0);
        }
        // ===== phase 1: (mh=1, ks=0)  [gate] =====
        {
            const int bA = par;
#pragma unroll
            for (int m = 0; m < 4; ++m)
                fA[m] = *(const bf16x8*)&sA[bA + kb * 2048 + (wrw * 128 + 64 + m * 16 + rr) * 8];
            if (pf) stageB(t + 1, 0);
            __builtin_amdgcn_s_barrier();
            asm volatile("s_waitcnt lgkmcnt(0)" ::: "memory");
            __builtin_amdgcn_sched_barrier(0);
            __builtin_amdgcn_s_setprio(1);
#pragma unroll
            for (int m = 0; m < 4; ++m)
#pragma unroll
                for (int n = 0; n < 4; ++n)
                    acc[4 + m][n] = __builtin_amdgcn_mfma_f32_16x16x32_bf16(fA[m], fB[n], acc[4 + m][n], 0, 0, 0);
            __builtin_amdgcn_s_setprio(0);
            if (pf) asm volatile("s_waitcnt vmcnt(4)" ::: "memory");
            else    asm volatile("s_waitcnt vmcnt(0)" ::: "memory");
            __builtin_amdgcn_s_barrier();
            __builtin_amdgcn_sched_barrier(0);
        }
        // ===== phase 2: (mh=0, ks=1) =====
        {
            const int bA = par + 8192, bB = par + 8192;
#pragma unroll
            for (int n = 0; n < 4; ++n)
                fB[n] = *(const bf16x8*)&sB[bB + kb * 2048 + (wcw * 64 + n * 16 + rr) * 8];
#pragma unroll
            for (int m = 0; m < 4; ++m)
                fA[m] = *(const bf16x8*)&sA[bA + kb * 2048 + (wrw * 128 + m * 16 + rr) * 8];
            if (pf) stageA(t + 1, 1);
            __builtin_amdgcn_s_barrier();
            asm volatile("s_waitcnt lgkmcnt(0)" ::: "memory");
            __builtin_amdgcn_sched_barrier(0);
            __builtin_amdgcn_s_setprio(1);
#pragma unroll
            for (int m = 0; m < 4; ++m)
#pragma unroll
                for (int n = 0; n < 4; ++n)
                    acc[m][n] = __builtin_amdgcn_mfma_f32_16x16x32_bf16(fA[m], fB[n], acc[m][n], 0, 0, 0);
            __builtin_amdgcn_s_setprio(0);
            __builtin_amdgcn_s_barrier();
            __builtin_amdgcn_sched_barrier(0);
        }
        // ===== phase 3: (mh=1, ks=1)  [gate] =====
        {
            const int bA = par + 8192;
#pragma unroll
            for (int m = 0; m < 4; ++m)
                fA[m] = *(const bf16x8*)&sA[bA + kb * 2048 + (wrw * 128 + 64 + m * 16 + rr) * 8];
            if (pf) stageB(t + 1, 1);
            __builtin_amdgcn_s_barrier();
            asm volatile("s_waitcnt lgkmcnt(0)" ::: "memory");
            __builtin_amdgcn_sched_barrier(0);
            __builtin_amdgcn_s_setprio(1);
#pragma unroll
            for (int m = 0; m < 4; ++m)
#pragma unroll
                for (int n = 0; n < 4; ++n)
                    acc[4 + m][n] = __builtin_amdgcn_mfma_f32_16x16x32_bf16(fA[m], fB[n], acc[4 + m][n], 0, 0, 0);
            __builtin_amdgcn_s_setprio(0);
            if (pf) asm volatile("s_waitcnt vmcnt(4)" ::: "memory");
            else    asm volatile("s_waitcnt vmcnt(0)" ::: "memory");
            __builtin_amdgcn_s_barrier();
            __builtin_amdgcn_sched_barrier(0);
        }
    }

    const int rq = lane >> 4;
#pragma unroll
    for (int m = 0; m < 8; ++m)
#pragma unroll
        for (int n = 0; n < 4; ++n) {
            int col = bn * 256 + wcw * 64 + n * 16 + rr;
            int row0 = bm * 256 + wrw * 128 + m * 16 + rq * 4;
#pragma unroll
            for (int j = 0; j < 4; ++j)
                C[(size_t)(row0 + j) * ldc + col] = acc[m][n][j];
        }
}

// ============ 128x128 split-bf16 MFMA GEMM (out_proj; depth-2 prefetch) ============
__global__ __launch_bounds__(256, 2) void gemm_split(const __bf16* __restrict__ Ah,
                                                     const __bf16* __restrict__ Al,
                                                     const __bf16* __restrict__ Bh,
                                                     const __bf16* __restrict__ Bl,
                                                     float* __restrict__ C,
                                                     int K, int ldc) {
    __shared__ __bf16 sAh[2][4096], sAl[2][4096], sBh[2][4096], sBl[2][4096];
    const int tid = threadIdx.x;
    const int lane = tid & 63;
    const int wid = tid >> 6;
    const int wrw = wid >> 1, wcw = wid & 1;
    const int bm = blockIdx.y, bn = blockIdx.x;

    const int r = tid & 127;
    const int kbq8 = (tid >> 7) * 8;
    const size_t arow = (size_t)(bm * 128 + r) * K;
    const size_t brow = (size_t)(bn * 128 + r) * K;

    f32x4 acc[4][4];
#pragma unroll
    for (int m = 0; m < 4; ++m)
#pragma unroll
        for (int n = 0; n < 4; ++n) acc[m][n] = (f32x4){0.f, 0.f, 0.f, 0.f};

    const int kb = lane >> 4, rr = lane & 15;

    auto stage = [&](int b, int k0) {
#pragma unroll
        for (int q = 0; q < 2; ++q) {
            const int lo = q * 2048 + tid * 8;
            const size_t go = (size_t)k0 + q * 16 + kbq8;
            gl_lds16(Ah + arow + go, &sAh[b][lo]);
            gl_lds16(Al + arow + go, &sAl[b][lo]);
            gl_lds16(Bh + brow + go, &sBh[b][lo]);
            gl_lds16(Bl + brow + go, &sBl[b][lo]);
        }
    };

    const int nt = K >> 5;
    stage(0, 0);
    stage(1, 32);
    asm volatile("s_waitcnt vmcnt(8)" ::: "memory");
    __builtin_amdgcn_s_barrier();

    for (int t = 0; t < nt; ++t) {
        const int cur = t & 1;
        bf16x8 fAh[4], fAl[4], fBh[4], fBl[4];
#pragma unroll
        for (int m = 0; m < 4; ++m) {
            int off = kb * 1024 + (wrw * 64 + m * 16 + rr) * 8;
            fAh[m] = *(const bf16x8*)&sAh[cur][off];
            fAl[m] = *(const bf16x8*)&sAl[cur][off];
        }
#pragma unroll
        for (int n = 0; n < 4; ++n) {
            int off = kb * 1024 + (wcw * 64 + n * 16 + rr) * 8;
            fBh[n] = *(const bf16x8*)&sBh[cur][off];
            fBl[n] = *(const bf16x8*)&sBl[cur][off];
        }
        asm volatile("s_waitcnt lgkmcnt(0)" ::: "memory");
        __builtin_amdgcn_sched_barrier(0);
        __builtin_amdgcn_s_barrier();
        __builtin_amdgcn_sched_barrier(0);
        if (t + 2 < nt) stage(cur, (t + 2) << 5);
        __builtin_amdgcn_s_setprio(1);
#pragma unroll
        for (int m = 0; m < 4; ++m)
#pragma unroll
            for (int n = 0; n < 4; ++n) {
                acc[m][n] = __builtin_amdgcn_mfma_f32_16x16x32_bf16(fAh[m], fBh[n], acc[m][n], 0, 0, 0);
                acc[m][n] = __builtin_amdgcn_mfma_f32_16x16x32_bf16(fAh[m], fBl[n], acc[m][n], 0, 0, 0);
                acc[m][n] = __builtin_amdgcn_mfma_f32_16x16x32_bf16(fAl[m], fBh[n], acc[m][n], 0, 0, 0);
            }
        __builtin_amdgcn_s_setprio(0);
        if (t + 2 < nt) asm volatile("s_waitcnt vmcnt(8)" ::: "memory");
        else            asm volatile("s_waitcnt vmcnt(0)" ::: "memory");
        __builtin_amdgcn_s_barrier();
    }

    const int rq = lane >> 4;
#pragma unroll
    for (int m = 0; m < 4; ++m)
#pragma unroll
        for (int n = 0; n < 4; ++n) {
            int col = bn * 128 + wcw * 64 + n * 16 + rr;
            int row0 = bm * 128 + wrw * 64 + m * 16 + rq * 4;
#pragma unroll
            for (int j = 0; j < 4; ++j)
                C[(size_t)(row0 + j) * ldc + col] = acc[m][n][j];
        }
}

// ============ scan phase 1: local chunk scans (fused conv+SiLU) ============
__global__ __launch_bounds__(256) void scan_phase1(const float* __restrict__ xz,
                                                   const float* __restrict__ coef,
                                                   const float* __restrict__ conv_w,
                                                   const float* __restrict__ conv_b,
                                                   float* __restrict__ states,
                                                   float* __restrict__ look) {
    int t = blockIdx.x * 256 + threadIdx.x;   // t = h*NC + c
    int c = t & (NC - 1);
    int h = t >> 5;

    const int HN = H_DIM * N_ST;
    float wr[N_ST], wi[N_ST];
#pragma unroll
    for (int n = 0; n < N_ST; ++n) {
        wr[n] = coef[h * N_ST + n];
        wi[n] = coef[HN + h * N_ST + n];
    }
    float cw0 = conv_w[h * 4 + 0], cw1 = conv_w[h * 4 + 1];
    float cw2 = conv_w[h * 4 + 2], cw3 = conv_w[h * 4 + 3];
    float cb = conv_b[h];

    const float* xrow = xz + (size_t)h * L_SEQ + c * CL;
    float x3 = 0.f, x2 = 0.f, x1 = 0.f;
    if (c > 0) {
        float4 p = *(const float4*)(xrow - 4);
        x3 = p.y; x2 = p.z; x1 = p.w;
    }
    *(float4*)(look + (size_t)t * 4) = make_float4(x3, x2, x1, 0.f);

    float sr[N_ST], si[N_ST];
#pragma unroll
    for (int n = 0; n < N_ST; ++n) { sr[n] = 0.f; si[n] = 0.f; }

    for (int j = 0; j < CL; j += 4) {
        float4 v = *(const float4*)(xrow + j);
        float xv[4] = {v.x, v.y, v.z, v.w};
#pragma unroll
        for (int k = 0; k < 4; ++k) {
            float u = cw0 * x3 + cw1 * x2 + cw2 * x1 + cw3 * xv[k] + cb;
            float xc = u / (1.f + __expf(-u));
            x3 = x2; x2 = x1; x1 = xv[k];
#pragma unroll
            for (int n = 0; n < N_ST; ++n) {
                float nr = wr[n] * sr[n] - wi[n] * si[n] + xc;
                float ni = wr[n] * si[n] + wi[n] * sr[n];
                sr[n] = nr; si[n] = ni;
            }
        }
    }
    float* st = states + (size_t)t * (N_ST * 2);
#pragma unroll
    for (int n = 0; n < N_ST; ++n) { st[2 * n] = sr[n]; st[2 * n + 1] = si[n]; }
}

// ============ scan phase 2: combine chunk states -> chunk init states ============
__global__ __launch_bounds__(256) void scan_phase2(const float* __restrict__ coef,
                                                   float* __restrict__ states) {
    int h = blockIdx.x * 256 + threadIdx.x;
    if (h >= H_DIM) return;
    const int HN = H_DIM * N_ST;
    float pr[N_ST], pi[N_ST];
#pragma unroll
    for (int n = 0; n < N_ST; ++n) {
        pr[n] = coef[4 * HN + h * N_ST + n];
        pi[n] = coef[5 * HN + h * N_ST + n];
    }
    float sr[N_ST], si[N_ST];
#pragma unroll
    for (int n = 0; n < N_ST; ++n) { sr[n] = 0.f; si[n] = 0.f; }
    float* base = states + (size_t)h * NC * (N_ST * 2);
    for (int c = 0; c < NC; ++c) {
        float* st = base + c * (N_ST * 2);
#pragma unroll
        for (int n = 0; n < N_ST; ++n) {
            float lr = st[2 * n], li = st[2 * n + 1];
            st[2 * n] = sr[n]; st[2 * n + 1] = si[n];
            float nr = pr[n] * sr[n] - pi[n] * si[n] + lr;
            float ni = pr[n] * si[n] + pi[n] * sr[n] + li;
            sr[n] = nr; si[n] = ni;
        }
    }
}

// ============ scan phase 3: replay, fused D-skip + gate; writes y f32 OVER x ============
__global__ __launch_bounds__(256) void scan_phase3(float* __restrict__ xz,
                                                   const float* __restrict__ coef,
                                                   const float* __restrict__ conv_w,
                                                   const float* __restrict__ conv_b,
                                                   const float* __restrict__ Dvec,
                                                   const float* __restrict__ states,
                                                   const float* __restrict__ look) {
    int t = blockIdx.x * 256 + threadIdx.x;
    int c = t & (NC - 1);
    int h = t >> 5;

    const int HN = H_DIM * N_ST;
    float wr[N_ST], wi[N_ST], Ctr[N_ST], Cti[N_ST];
#pragma unroll
    for (int n = 0; n < N_ST; ++n) {
        wr[n]  = coef[h * N_ST + n];
        wi[n]  = coef[HN + h * N_ST + n];
        Ctr[n] = coef[2 * HN + h * N_ST + n];
        Cti[n] = coef[3 * HN + h * N_ST + n];
    }
    float cw0 = conv_w[h * 4 + 0], cw1 = conv_w[h * 4 + 1];
    float cw2 = conv_w[h * 4 + 2], cw3 = conv_w[h * 4 + 3];
    float cb = conv_b[h];
    float Dh = Dvec[h];

    float* xrow = xz + (size_t)h * L_SEQ + c * CL;
    const float* zrow = xz + (size_t)(H_DIM + h) * L_SEQ + c * CL;

    float4 lk = *(const float4*)(look + (size_t)t * 4);
    float x3 = lk.x, x2 = lk.y, x1 = lk.z;

    const float* st = states + (size_t)t * (N_ST * 2);
    float sr[N_ST], si[N_ST];
#pragma unroll
    for (int n = 0; n < N_ST; ++n) { sr[n] = st[2 * n]; si[n] = st[2 * n + 1]; }

    for (int j = 0; j < CL; j += 4) {
        float4 v = *(const float4*)(xrow + j);
        float4 zv = *(const float4*)(zrow + j);
        float xv[4] = {v.x, v.y, v.z, v.w};
        float zz[4] = {zv.x, zv.y, zv.z, zv.w};
        float out[4];
#pragma unroll
        for (int k = 0; k < 4; ++k) {
            float u = cw0 * x3 + cw1 * x2 + cw2 * x1 + cw3 * xv[k] + cb;
            float xc = u / (1.f + __expf(-u));
            x3 = x2; x2 = x1; x1 = xv[k];
            float accy = 0.f;
#pragma unroll
            for (int n = 0; n < N_ST; ++n) {
                float nr = wr[n] * sr[n] - wi[n] * si[n] + xc;
                float ni = wr[n] * si[n] + wi[n] * sr[n];
                sr[n] = nr; si[n] = ni;
                accy += Ctr[n] * nr - Cti[n] * ni;
            }
            float yv = 2.f * accy + Dh * xc;
            float g = zz[k] / (1.f + __expf(-zz[k]));
            out[k] = yv * g;
        }
        *(float4*)(xrow + j) = make_float4(out[0], out[1], out[2], out[3]);
    }
}

// ============ transpose + split: y f32 [H][L] -> yTh/yTl bf16 [L][H] ============
__global__ __launch_bounds__(256) void transpose_split(const float* __restrict__ y,
                                                       __bf16* __restrict__ th,
                                                       __bf16* __restrict__ tl) {
    __shared__ float tile[64][65];
    const int l0 = blockIdx.x * 64, h0 = blockIdx.y * 64;
    const int tid = threadIdx.x;
    const int r = tid >> 4, c4 = (tid & 15) * 4;
#pragma unroll
    for (int p = 0; p < 4; ++p) {
        float4 v = *(const float4*)(y + (size_t)(h0 + r + p * 16) * L_SEQ + l0 + c4);
        tile[r + p * 16][c4 + 0] = v.x;
        tile[r + p * 16][c4 + 1] = v.y;
        tile[r + p * 16][c4 + 2] = v.z;
        tile[r + p * 16][c4 + 3] = v.w;
    }
    __syncthreads();
    const int l = tid >> 2, hb = (tid & 3) * 16;
    float vals[16];
#pragma unroll
    for (int j = 0; j < 16; ++j) vals[j] = tile[hb + j][l];
    bf16x8 hv0, hv1, lv0, lv1;
#pragma unroll
    for (int j = 0; j < 8; ++j) {
        __bf16 hbv = (__bf16)vals[j];
        hv0[j] = hbv;
        lv0[j] = (__bf16)(vals[j] - (float)hbv);
        __bf16 hbv2 = (__bf16)vals[j + 8];
        hv1[j] = hbv2;
        lv1[j] = (__bf16)(vals[j + 8] - (float)hbv2);
    }
    size_t base = (size_t)(l0 + l) * H_DIM + h0 + hb;
    *(bf16x8*)&th[base] = hv0;
    *(bf16x8*)&th[base + 8] = hv1;
    *(bf16x8*)&tl[base] = lv0;
    *(bf16x8*)&tl[base + 8] = lv1;
}

extern "C" void kernel_launch(void* const* d_in, const int* in_sizes, int n_in,
                              void* d_out, int out_size, void* d_ws, size_t ws_size,
                              hipStream_t stream) {
    const float* hid        = (const float*)d_in[0];
    const float* W_in       = (const float*)d_in[1];
    const float* conv_w     = (const float*)d_in[2];
    const float* conv_b     = (const float*)d_in[3];
    const float* log_dt     = (const float*)d_in[4];
    const float* log_A_real = (const float*)d_in[5];
    const float* A_imag     = (const float*)d_in[6];
    const float* C_re       = (const float*)d_in[7];
    const float* C_im       = (const float*)d_in[8];
    const float* Dv         = (const float*)d_in[9];
    const float* W_out      = (const float*)d_in[10];
    float* out = (float*)d_out;
    float* ws  = (float*)d_ws;

    float* xz      = ws + WS_XZ;
    __bf16* yTh    = (__bf16*)(ws + WS_YTH);
    __bf16* yTl    = (__bf16*)(ws + WS_YTL);
    float* coef    = ws + WS_COEF;
    float* states  = ws + WS_STATES;
    float* look    = ws + WS_LOOK;
    __bf16* Hf     = (__bf16*)(ws + WS_HF);
    __bf16* WiF    = (__bf16*)(ws + WS_WIF);
    __bf16* Woh    = (__bf16*)(ws + WS_WOH);
    __bf16* Wol    = (__bf16*)(ws + WS_WOL);

    coef_kernel<<<(H_DIM * N_ST + 255) / 256, 256, 0, stream>>>(
        log_dt, log_A_real, A_imag, C_re, C_im, coef);

    const int wOct = 2 * H_DIM * DMODEL / 8;   // 524288
    cvt_fuse<0><<<(wOct + 255) / 256, 256, 0, stream>>>(W_in, WiF, wOct);
    cvt_split4<<<(DMODEL * H_DIM / 4 + 255) / 256, 256, 0, stream>>>(W_out, Woh, Wol, DMODEL * H_DIM / 4);

    const int nscan = H_DIM * NC;              // 65536
    const int hOct = L_SEQ * DMODEL / 8;       // 524288
    dim3 gIn(L_SEQ / 256, 2 * H_DIM / 256);    // (16,16) = 256 blocks
    dim3 gOut(DMODEL / 128, L_SEQ / 128);      // (8,32)  = 256 blocks
    dim3 gTr(L_SEQ / 64, H_DIM / 64);          // (64,32)

    for (int b = 0; b < B_SZ; ++b) {
        const float* hid_b = hid + (size_t)b * L_SEQ * DMODEL;
        float* out_b = out + (size_t)b * L_SEQ * DMODEL;

        cvt_fuse<1><<<(hOct + 255) / 256, 256, 0, stream>>>(hid_b, Hf, hOct);
        gemm_f256p<<<gIn, 512, 0, stream>>>(WiF, Hf, xz, 3 * DMODEL, L_SEQ);
        scan_phase1<<<nscan / 256, 256, 0, stream>>>(xz, coef, conv_w, conv_b, states, look);
        scan_phase2<<<(H_DIM + 255) / 256, 256, 0, stream>>>(coef, states);
        scan_phase3<<<nscan / 256, 256, 0, stream>>>(xz, coef, conv_w, conv_b, Dv, states, look);
        transpose_split<<<gTr, 256, 0, stream>>>(xz, yTh, yTl);
        gemm_split<<<gOut, 256, 0, stream>>>(yTh, yTl, Woh, Wol, out_b, H_DIM, DMODEL);
    }
}

// Round 11
// 1467.086 us; speedup vs baseline: 1.3223x; 1.0298x over previous
//
#include <hip/hip_runtime.h>
#include <hip/hip_bf16.h>
#include <math.h>

#define H_DIM 2048
#define N_ST 8
#define B_SZ 4
#define L_SEQ 4096
#define DMODEL 1024
#define DCONV 4
#define CL 128
#define NC (L_SEQ / CL)   // 32

typedef __bf16 bf16x8 __attribute__((ext_vector_type(8)));
typedef __bf16 bf16x4 __attribute__((ext_vector_type(4)));
typedef float f32x4 __attribute__((ext_vector_type(4)));

typedef const unsigned int __attribute__((address_space(1)))* gptr_t;
typedef unsigned int __attribute__((address_space(3)))* lptr_t;

__device__ __forceinline__ void gl_lds16(const __bf16* g, __bf16* l) {
    __builtin_amdgcn_global_load_lds((gptr_t)g, (lptr_t)l, 16, 0, 0);
}

// -------- workspace layout (floats), total ~32.9M f = 131.5 MB --------
#define WS_XZ     0
#define WS_YTH    8388608
#define WS_YTL    12582912
#define WS_COEF   16777216
#define WS_STATES 16875520
#define WS_LOOK   17924096
#define WS_HF     18186240   // fused hid  bf16 [4096][3072]
#define WS_WIF    24477696   // fused W_in bf16 [4096][3072]
#define WS_WOH    30769152   // W_out hi plane bf16 [1024][2048]
#define WS_WOL    31817728   // W_out lo plane

// ============ split f32 -> bf16 hi/lo planes (for W_out) ============
__global__ __launch_bounds__(256) void cvt_split4(const float* __restrict__ s,
                                                  __bf16* __restrict__ h,
                                                  __bf16* __restrict__ l, int n4) {
    int i = blockIdx.x * 256 + threadIdx.x;
    if (i >= n4) return;
    float4 v = ((const float4*)s)[i];
    float vv[4] = {v.x, v.y, v.z, v.w};
    bf16x4 hv, lv;
#pragma unroll
    for (int j = 0; j < 4; ++j) {
        __bf16 hb = (__bf16)vv[j];
        hv[j] = hb;
        lv[j] = (__bf16)(vv[j] - (float)hb);
    }
    *(bf16x4*)&h[(size_t)i * 4] = hv;
    *(bf16x4*)&l[(size_t)i * 4] = lv;
}

// ============ fuse f32 [R][1024] -> bf16 [R][3072] triplet octs ============
// A-side: [h][h][l]; B-side: [h][l][h]  =>  sum = AhBh + AhBl + AlBh.
template <int BSIDE>
__global__ __launch_bounds__(256) void cvt_fuse(const float* __restrict__ s,
                                                __bf16* __restrict__ d, int nOct) {
    int i = blockIdx.x * 256 + threadIdx.x;
    if (i >= nOct) return;
    int row = i >> 7, ko = i & 127;          // K=1024 -> 128 octs/row
    const float* p = s + (size_t)row * 1024 + ko * 8;
    float4 v0 = *(const float4*)p;
    float4 v1 = *(const float4*)(p + 4);
    float vv[8] = {v0.x, v0.y, v0.z, v0.w, v1.x, v1.y, v1.z, v1.w};
    bf16x8 hv, lv;
#pragma unroll
    for (int j = 0; j < 8; ++j) {
        __bf16 hb = (__bf16)vv[j];
        hv[j] = hb;
        lv[j] = (__bf16)(vv[j] - (float)hb);
    }
    __bf16* o = d + (size_t)row * 3072 + ko * 24;
    if (BSIDE) {
        *(bf16x8*)(o) = hv; *(bf16x8*)(o + 8) = lv; *(bf16x8*)(o + 16) = hv;
    } else {
        *(bf16x8*)(o) = hv; *(bf16x8*)(o + 8) = hv; *(bf16x8*)(o + 16) = lv;
    }
}

// ============ coefficient precompute ============
__global__ void coef_kernel(const float* __restrict__ log_dt,
                            const float* __restrict__ log_A_real,
                            const float* __restrict__ A_imag,
                            const float* __restrict__ C_re,
                            const float* __restrict__ C_im,
                            float* __restrict__ coef) {
    int i = blockIdx.x * blockDim.x + threadIdx.x;
    if (i >= H_DIM * N_ST) return;
    int h = i >> 3;
    float dt = expf(log_dt[h]);
    float Ar = -expf(log_A_real[i]);
    float Ai = A_imag[i];
    float er = expf(dt * Ar);
    float ang = dt * Ai;
    float wr = er * cosf(ang);
    float wi = er * sinf(ang);
    float den = Ar * Ar + Ai * Ai;
    float qr = ((wr - 1.f) * Ar + wi * Ai) / den;
    float qi = (wi * Ar - (wr - 1.f) * Ai) / den;
    float Cr = C_re[i], Ci = C_im[i];
    float Ctr = Cr * qr - Ci * qi;
    float Cti = Cr * qi + Ci * qr;
    float eCL = expf((float)CL * dt * Ar);
    float aCL = (float)CL * dt * Ai;
    float pr = eCL * cosf(aCL);
    float pi = eCL * sinf(aCL);
    const int HN = H_DIM * N_ST;
    coef[i]          = wr;
    coef[HN + i]     = wi;
    coef[2 * HN + i] = Ctr;
    coef[3 * HN + i] = Cti;
    coef[4 * HN + i] = pr;
    coef[5 * HN + i] = pi;
}

// ============ 256x256 fused bf16 GEMM — 4-phase/K-half schedule (round-10 WIN) ============
__global__ __launch_bounds__(512, 2) void gemm_f256p(const __bf16* __restrict__ A,
                                                     const __bf16* __restrict__ B,
                                                     float* __restrict__ C,
                                                     int K, int ldc) {
    __shared__ __bf16 sA[32768], sB[32768];   // [par][ks][kb][256 rows][8] each
    const int tid = threadIdx.x;
    const int lane = tid & 63;
    const int wid = tid >> 6;
    const int wrw = wid >> 2, wcw = wid & 3;
    const int bm = blockIdx.y, bn = blockIdx.x;

    f32x4 acc[8][4];
#pragma unroll
    for (int m = 0; m < 8; ++m)
#pragma unroll
        for (int n = 0; n < 4; ++n) acc[m][n] = (f32x4){0.f, 0.f, 0.f, 0.f};

    const int kb = lane >> 4, rr = lane & 15;

    const int f0 = tid, f1 = 512 + tid;
    const int kA0 = f0 >> 8, rA0 = f0 & 255;
    const int kA1 = f1 >> 8, rA1 = f1 & 255;
    const size_t gA0 = (size_t)(bm * 256 + rA0) * K;
    const size_t gA1 = (size_t)(bm * 256 + rA1) * K;
    const size_t gB0 = (size_t)(bn * 256 + rA0) * K;
    const size_t gB1 = (size_t)(bn * 256 + rA1) * K;
    const int dst0 = kA0 * 2048 + rA0 * 8;
    const int dst1 = kA1 * 2048 + rA1 * 8;

    auto stageA = [&](int t, int ks) {
        const int base = (t & 1) * 16384 + ks * 8192;
        const size_t go = (size_t)t * 64 + ks * 32;
        gl_lds16(A + gA0 + go + kA0 * 8, &sA[base + dst0]);
        gl_lds16(A + gA1 + go + kA1 * 8, &sA[base + dst1]);
    };
    auto stageB = [&](int t, int ks) {
        const int base = (t & 1) * 16384 + ks * 8192;
        const size_t go = (size_t)t * 64 + ks * 32;
        gl_lds16(B + gB0 + go + kA0 * 8, &sB[base + dst0]);
        gl_lds16(B + gB1 + go + kA1 * 8, &sB[base + dst1]);
    };

    const int nt = K >> 6;   // BK=64
    stageA(0, 0); stageB(0, 0); stageA(0, 1); stageB(0, 1);
    asm volatile("s_waitcnt vmcnt(0)" ::: "memory");
    __builtin_amdgcn_s_barrier();
    __builtin_amdgcn_sched_barrier(0);

#pragma unroll 1
    for (int t = 0; t < nt; ++t) {
        const int par = (t & 1) * 16384;
        const bool pf = (t + 1 < nt);
        bf16x8 fB[4], fA[4];

        // ===== phase 0: (mh=0, ks=0) =====
        {
            const int bA = par, bB = par;
#pragma unroll
            for (int n = 0; n < 4; ++n)
                fB[n] = *(const bf16x8*)&sB[bB + kb * 2048 + (wcw * 64 + n * 16 + rr) * 8];
#pragma unroll
            for (int m = 0; m < 4; ++m)
                fA[m] = *(const bf16x8*)&sA[bA + kb * 2048 + (wrw * 128 + m * 16 + rr) * 8];
            if (pf) stageA(t + 1, 0);
            __builtin_amdgcn_s_barrier();
            asm volatile("s_waitcnt lgkmcnt(0)" ::: "memory");
            __builtin_amdgcn_sched_barrier(0);
            __builtin_amdgcn_s_setprio(1);
#pragma unroll
            for (int m = 0; m < 4; ++m)
#pragma unroll
                for (int n = 0; n < 4; ++n)
                    acc[m][n] = __builtin_amdgcn_mfma_f32_16x16x32_bf16(fA[m], fB[n], acc[m][n], 0, 0, 0);
            __builtin_amdgcn_s_setprio(0);
            __builtin_amdgcn_s_barrier();
            __builtin_amdgcn_sched_barrier(0);
        }
        // ===== phase 1: (mh=1, ks=0)  [gate] =====
        {
            const int bA = par;
#pragma unroll
            for (int m = 0; m < 4; ++m)
                fA[m] = *(const bf16x8*)&sA[bA + kb * 2048 + (wrw * 128 + 64 + m * 16 + rr) * 8];
            if (pf) stageB(t + 1, 0);
            __builtin_amdgcn_s_barrier();
            asm volatile("s_waitcnt lgkmcnt(0)" ::: "memory");
            __builtin_amdgcn_sched_barrier(0);
            __builtin_amdgcn_s_setprio(1);
#pragma unroll
            for (int m = 0; m < 4; ++m)
#pragma unroll
                for (int n = 0; n < 4; ++n)
                    acc[4 + m][n] = __builtin_amdgcn_mfma_f32_16x16x32_bf16(fA[m], fB[n], acc[4 + m][n], 0, 0, 0);
            __builtin_amdgcn_s_setprio(0);
            if (pf) asm volatile("s_waitcnt vmcnt(4)" ::: "memory");
            else    asm volatile("s_waitcnt vmcnt(0)" ::: "memory");
            __builtin_amdgcn_s_barrier();
            __builtin_amdgcn_sched_barrier(0);
        }
        // ===== phase 2: (mh=0, ks=1) =====
        {
            const int bA = par + 8192, bB = par + 8192;
#pragma unroll
            for (int n = 0; n < 4; ++n)
                fB[n] = *(const bf16x8*)&sB[bB + kb * 2048 + (wcw * 64 + n * 16 + rr) * 8];
#pragma unroll
            for (int m = 0; m < 4; ++m)
                fA[m] = *(const bf16x8*)&sA[bA + kb * 2048 + (wrw * 128 + m * 16 + rr) * 8];
            if (pf) stageA(t + 1, 1);
            __builtin_amdgcn_s_barrier();
            asm volatile("s_waitcnt lgkmcnt(0)" ::: "memory");
            __builtin_amdgcn_sched_barrier(0);
            __builtin_amdgcn_s_setprio(1);
#pragma unroll
            for (int m = 0; m < 4; ++m)
#pragma unroll
                for (int n = 0; n < 4; ++n)
                    acc[m][n] = __builtin_amdgcn_mfma_f32_16x16x32_bf16(fA[m], fB[n], acc[m][n], 0, 0, 0);
            __builtin_amdgcn_s_setprio(0);
            __builtin_amdgcn_s_barrier();
            __builtin_amdgcn_sched_barrier(0);
        }
        // ===== phase 3: (mh=1, ks=1)  [gate] =====
        {
            const int bA = par + 8192;
#pragma unroll
            for (int m = 0; m < 4; ++m)
                fA[m] = *(const bf16x8*)&sA[bA + kb * 2048 + (wrw * 128 + 64 + m * 16 + rr) * 8];
            if (pf) stageB(t + 1, 1);
            __builtin_amdgcn_s_barrier();
            asm volatile("s_waitcnt lgkmcnt(0)" ::: "memory");
            __builtin_amdgcn_sched_barrier(0);
            __builtin_amdgcn_s_setprio(1);
#pragma unroll
            for (int m = 0; m < 4; ++m)
#pragma unroll
                for (int n = 0; n < 4; ++n)
                    acc[4 + m][n] = __builtin_amdgcn_mfma_f32_16x16x32_bf16(fA[m], fB[n], acc[4 + m][n], 0, 0, 0);
            __builtin_amdgcn_s_setprio(0);
            if (pf) asm volatile("s_waitcnt vmcnt(4)" ::: "memory");
            else    asm volatile("s_waitcnt vmcnt(0)" ::: "memory");
            __builtin_amdgcn_s_barrier();
            __builtin_amdgcn_sched_barrier(0);
        }
    }

    const int rq = lane >> 4;
#pragma unroll
    for (int m = 0; m < 8; ++m)
#pragma unroll
        for (int n = 0; n < 4; ++n) {
            int col = bn * 256 + wcw * 64 + n * 16 + rr;
            int row0 = bm * 256 + wrw * 128 + m * 16 + rq * 4;
#pragma unroll
            for (int j = 0; j < 4; ++j)
                C[(size_t)(row0 + j) * ldc + col] = acc[m][n][j];
        }
}

// ============ 128x128 split-plane GEMM with the 4-phase/ks-split fine schedule ============
// C[M][N] = sum_k Ah/Al[m][k] x Bh/Bl[n][k], 3-term. BK=64 (2 ks-halves), 4 waves (2x2),
// LDS 128 KiB: [par][ks] x 4 planes x 8 KB. Per phase: {reads | stage plane-pair |
// barrier | lgkm | setprio 24 MFMA | [vmcnt(8) gate at ph1/ph3] | barrier}.
__global__ __launch_bounds__(256, 1) void gemm_s128p(const __bf16* __restrict__ Ah,
                                                     const __bf16* __restrict__ Al,
                                                     const __bf16* __restrict__ Bh,
                                                     const __bf16* __restrict__ Bl,
                                                     float* __restrict__ C,
                                                     int K, int ldc) {
    __shared__ __bf16 sAh[2][2][4096], sAl[2][2][4096];
    __shared__ __bf16 sBh[2][2][4096], sBl[2][2][4096];
    const int tid = threadIdx.x;
    const int lane = tid & 63;
    const int wid = tid >> 6;
    const int wrw = wid >> 1, wcw = wid & 1;
    const int bm = blockIdx.y, bn = blockIdx.x;

    f32x4 acc[4][4];
#pragma unroll
    for (int m = 0; m < 4; ++m)
#pragma unroll
        for (int n = 0; n < 4; ++n) acc[m][n] = (f32x4){0.f, 0.f, 0.f, 0.f};

    const int kb = lane >> 4, rr = lane & 15;

    // staging lines: f = l*256+tid -> kbs = f>>7 (0..3), row = f&127
    const int fl0 = tid, fl1 = 256 + tid;
    const int kbs0 = fl0 >> 7, rw0 = fl0 & 127;
    const int kbs1 = fl1 >> 7, rw1 = fl1 & 127;
    const size_t gAr0 = (size_t)(bm * 128 + rw0) * K;
    const size_t gAr1 = (size_t)(bm * 128 + rw1) * K;
    const size_t gBr0 = (size_t)(bn * 128 + rw0) * K;
    const size_t gBr1 = (size_t)(bn * 128 + rw1) * K;
    const int d0 = kbs0 * 1024 + rw0 * 8;
    const int d1 = kbs1 * 1024 + rw1 * 8;

    auto stA = [&](int t, int ks) {   // 4 loads: Ah+Al, 2 lines each
        const int par = t & 1;
        const size_t go = (size_t)t * 64 + ks * 32;
        gl_lds16(Ah + gAr0 + go + kbs0 * 8, &sAh[par][ks][d0]);
        gl_lds16(Ah + gAr1 + go + kbs1 * 8, &sAh[par][ks][d1]);
        gl_lds16(Al + gAr0 + go + kbs0 * 8, &sAl[par][ks][d0]);
        gl_lds16(Al + gAr1 + go + kbs1 * 8, &sAl[par][ks][d1]);
    };
    auto stB = [&](int t, int ks) {
        const int par = t & 1;
        const size_t go = (size_t)t * 64 + ks * 32;
        gl_lds16(Bh + gBr0 + go + kbs0 * 8, &sBh[par][ks][d0]);
        gl_lds16(Bh + gBr1 + go + kbs1 * 8, &sBh[par][ks][d1]);
        gl_lds16(Bl + gBr0 + go + kbs0 * 8, &sBl[par][ks][d0]);
        gl_lds16(Bl + gBr1 + go + kbs1 * 8, &sBl[par][ks][d1]);
    };

    const int nt = K >> 6;   // BK=64
    stA(0, 0); stB(0, 0); stA(0, 1); stB(0, 1);
    asm volatile("s_waitcnt vmcnt(0)" ::: "memory");
    __builtin_amdgcn_s_barrier();
    __builtin_amdgcn_sched_barrier(0);

    bf16x8 fAh[4], fAl[4], fBh[4], fBl[4];

#pragma unroll 1
    for (int t = 0; t < nt; ++t) {
        const int par = t & 1;
        const bool pf = (t + 1 < nt);

        // ===== phase 0 (ks=0): read all 16 frags, stage A(t+1,ks0), MFMA m0,m1 =====
        {
#pragma unroll
            for (int n = 0; n < 4; ++n) {
                const int off = kb * 1024 + (wcw * 64 + n * 16 + rr) * 8;
                fBh[n] = *(const bf16x8*)&sBh[par][0][off];
                fBl[n] = *(const bf16x8*)&sBl[par][0][off];
            }
#pragma unroll
            for (int m = 0; m < 4; ++m) {
                const int off = kb * 1024 + (wrw * 64 + m * 16 + rr) * 8;
                fAh[m] = *(const bf16x8*)&sAh[par][0][off];
                fAl[m] = *(const bf16x8*)&sAl[par][0][off];
            }
            if (pf) stA(t + 1, 0);
            __builtin_amdgcn_s_barrier();
            asm volatile("s_waitcnt lgkmcnt(0)" ::: "memory");
            __builtin_amdgcn_sched_barrier(0);
            __builtin_amdgcn_s_setprio(1);
#pragma unroll
            for (int m = 0; m < 2; ++m)
#pragma unroll
                for (int n = 0; n < 4; ++n) {
                    acc[m][n] = __builtin_amdgcn_mfma_f32_16x16x32_bf16(fAh[m], fBh[n], acc[m][n], 0, 0, 0);
                    acc[m][n] = __builtin_amdgcn_mfma_f32_16x16x32_bf16(fAh[m], fBl[n], acc[m][n], 0, 0, 0);
                    acc[m][n] = __builtin_amdgcn_mfma_f32_16x16x32_bf16(fAl[m], fBh[n], acc[m][n], 0, 0, 0);
                }
            __builtin_amdgcn_s_setprio(0);
            __builtin_amdgcn_s_barrier();
            __builtin_amdgcn_sched_barrier(0);
        }
        // ===== phase 1 (ks=0): stage B(t+1,ks0), MFMA m2,m3, gate =====
        {
            if (pf) stB(t + 1, 0);
            __builtin_amdgcn_s_barrier();
            __builtin_amdgcn_sched_barrier(0);
            __builtin_amdgcn_s_setprio(1);
#pragma unroll
            for (int m = 2; m < 4; ++m)
#pragma unroll
                for (int n = 0; n < 4; ++n) {
                    acc[m][n] = __builtin_amdgcn_mfma_f32_16x16x32_bf16(fAh[m], fBh[n], acc[m][n], 0, 0, 0);
                    acc[m][n] = __builtin_amdgcn_mfma_f32_16x16x32_bf16(fAh[m], fBl[n], acc[m][n], 0, 0, 0);
                    acc[m][n] = __builtin_amdgcn_mfma_f32_16x16x32_bf16(fAl[m], fBh[n], acc[m][n], 0, 0, 0);
                }
            __builtin_amdgcn_s_setprio(0);
            // wait for this tile's ks1 pieces (staged last tile) before ph2 reads them
            if (pf) asm volatile("s_waitcnt vmcnt(8)" ::: "memory");
            else    asm volatile("s_waitcnt vmcnt(0)" ::: "memory");
            __builtin_amdgcn_s_barrier();
            __builtin_amdgcn_sched_barrier(0);
        }
        // ===== phase 2 (ks=1): read all 16 frags, stage A(t+1,ks1), MFMA m0,m1 =====
        {
#pragma unroll
            for (int n = 0; n < 4; ++n) {
                const int off = kb * 1024 + (wcw * 64 + n * 16 + rr) * 8;
                fBh[n] = *(const bf16x8*)&sBh[par][1][off];
                fBl[n] = *(const bf16x8*)&sBl[par][1][off];
            }
#pragma unroll
            for (int m = 0; m < 4; ++m) {
                const int off = kb * 1024 + (wrw * 64 + m * 16 + rr) * 8;
                fAh[m] = *(const bf16x8*)&sAh[par][1][off];
                fAl[m] = *(const bf16x8*)&sAl[par][1][off];
            }
            if (pf) stA(t + 1, 1);
            __builtin_amdgcn_s_barrier();
            asm volatile("s_waitcnt lgkmcnt(0)" ::: "memory");
            __builtin_amdgcn_sched_barrier(0);
            __builtin_amdgcn_s_setprio(1);
#pragma unroll
            for (int m = 0; m < 2; ++m)
#pragma unroll
                for (int n = 0; n < 4; ++n) {
                    acc[m][n] = __builtin_amdgcn_mfma_f32_16x16x32_bf16(fAh[m], fBh[n], acc[m][n], 0, 0, 0);
                    acc[m][n] = __builtin_amdgcn_mfma_f32_16x16x32_bf16(fAh[m], fBl[n], acc[m][n], 0, 0, 0);
                    acc[m][n] = __builtin_amdgcn_mfma_f32_16x16x32_bf16(fAl[m], fBh[n], acc[m][n], 0, 0, 0);
                }
            __builtin_amdgcn_s_setprio(0);
            __builtin_amdgcn_s_barrier();
            __builtin_amdgcn_sched_barrier(0);
        }
        // ===== phase 3 (ks=1): stage B(t+1,ks1), MFMA m2,m3, gate =====
        {
            if (pf) stB(t + 1, 1);
            __builtin_amdgcn_s_barrier();
            __builtin_amdgcn_sched_barrier(0);
            __builtin_amdgcn_s_setprio(1);
#pragma unroll
            for (int m = 2; m < 4; ++m)
#pragma unroll
                for (int n = 0; n < 4; ++n) {
                    acc[m][n] = __builtin_amdgcn_mfma_f32_16x16x32_bf16(fAh[m], fBh[n], acc[m][n], 0, 0, 0);
                    acc[m][n] = __builtin_amdgcn_mfma_f32_16x16x32_bf16(fAh[m], fBl[n], acc[m][n], 0, 0, 0);
                    acc[m][n] = __builtin_amdgcn_mfma_f32_16x16x32_bf16(fAl[m], fBh[n], acc[m][n], 0, 0, 0);
                }
            __builtin_amdgcn_s_setprio(0);
            // wait for next tile's ks0 pieces before its ph0 reads
            if (pf) asm volatile("s_waitcnt vmcnt(8)" ::: "memory");
            else    asm volatile("s_waitcnt vmcnt(0)" ::: "memory");
            __builtin_amdgcn_s_barrier();
            __builtin_amdgcn_sched_barrier(0);
        }
    }

    const int rq = lane >> 4;
#pragma unroll
    for (int m = 0; m < 4; ++m)
#pragma unroll
        for (int n = 0; n < 4; ++n) {
            int col = bn * 128 + wcw * 64 + n * 16 + rr;
            int row0 = bm * 128 + wrw * 64 + m * 16 + rq * 4;
#pragma unroll
            for (int j = 0; j < 4; ++j)
                C[(size_t)(row0 + j) * ldc + col] = acc[m][n][j];
        }
}

// ============ scan phase 1: local chunk scans (fused conv+SiLU) ============
__global__ __launch_bounds__(256) void scan_phase1(const float* __restrict__ xz,
                                                   const float* __restrict__ coef,
                                                   const float* __restrict__ conv_w,
                                                   const float* __restrict__ conv_b,
                                                   float* __restrict__ states,
                                                   float* __restrict__ look) {
    int t = blockIdx.x * 256 + threadIdx.x;   // t = h*NC + c
    int c = t & (NC - 1);
    int h = t >> 5;

    const int HN = H_DIM * N_ST;
    float wr[N_ST], wi[N_ST];
#pragma unroll
    for (int n = 0; n < N_ST; ++n) {
        wr[n] = coef[h * N_ST + n];
        wi[n] = coef[HN + h * N_ST + n];
    }
    float cw0 = conv_w[h * 4 + 0], cw1 = conv_w[h * 4 + 1];
    float cw2 = conv_w[h * 4 + 2], cw3 = conv_w[h * 4 + 3];
    float cb = conv_b[h];

    const float* xrow = xz + (size_t)h * L_SEQ + c * CL;
    float x3 = 0.f, x2 = 0.f, x1 = 0.f;
    if (c > 0) {
        float4 p = *(const float4*)(xrow - 4);
        x3 = p.y; x2 = p.z; x1 = p.w;
    }
    *(float4*)(look + (size_t)t * 4) = make_float4(x3, x2, x1, 0.f);

    float sr[N_ST], si[N_ST];
#pragma unroll
    for (int n = 0; n < N_ST; ++n) { sr[n] = 0.f; si[n] = 0.f; }

    for (int j = 0; j < CL; j += 4) {
        float4 v = *(const float4*)(xrow + j);
        float xv[4] = {v.x, v.y, v.z, v.w};
#pragma unroll
        for (int k = 0; k < 4; ++k) {
            float u = cw0 * x3 + cw1 * x2 + cw2 * x1 + cw3 * xv[k] + cb;
            float xc = u / (1.f + __expf(-u));
            x3 = x2; x2 = x1; x1 = xv[k];
#pragma unroll
            for (int n = 0; n < N_ST; ++n) {
                float nr = wr[n] * sr[n] - wi[n] * si[n] + xc;
                float ni = wr[n] * si[n] + wi[n] * sr[n];
                sr[n] = nr; si[n] = ni;
            }
        }
    }
    float* st = states + (size_t)t * (N_ST * 2);
#pragma unroll
    for (int n = 0; n < N_ST; ++n) { st[2 * n] = sr[n]; st[2 * n + 1] = si[n]; }
}

// ============ scan phase 2: combine chunk states -> chunk init states ============
__global__ __launch_bounds__(256) void scan_phase2(const float* __restrict__ coef,
                                                   float* __restrict__ states) {
    int h = blockIdx.x * 256 + threadIdx.x;
    if (h >= H_DIM) return;
    const int HN = H_DIM * N_ST;
    float pr[N_ST], pi[N_ST];
#pragma unroll
    for (int n = 0; n < N_ST; ++n) {
        pr[n] = coef[4 * HN + h * N_ST + n];
        pi[n] = coef[5 * HN + h * N_ST + n];
    }
    float sr[N_ST], si[N_ST];
#pragma unroll
    for (int n = 0; n < N_ST; ++n) { sr[n] = 0.f; si[n] = 0.f; }
    float* base = states + (size_t)h * NC * (N_ST * 2);
    for (int c = 0; c < NC; ++c) {
        float* st = base + c * (N_ST * 2);
#pragma unroll
        for (int n = 0; n < N_ST; ++n) {
            float lr = st[2 * n], li = st[2 * n + 1];
            st[2 * n] = sr[n]; st[2 * n + 1] = si[n];
            float nr = pr[n] * sr[n] - pi[n] * si[n] + lr;
            float ni = pr[n] * si[n] + pi[n] * sr[n] + li;
            sr[n] = nr; si[n] = ni;
        }
    }
}

// ============ scan phase 3: replay, fused D-skip + gate; writes y f32 OVER x ============
__global__ __launch_bounds__(256) void scan_phase3(float* __restrict__ xz,
                                                   const float* __restrict__ coef,
                                                   const float* __restrict__ conv_w,
                                                   const float* __restrict__ conv_b,
                                                   const float* __restrict__ Dvec,
                                                   const float* __restrict__ states,
                                                   const float* __restrict__ look) {
    int t = blockIdx.x * 256 + threadIdx.x;
    int c = t & (NC - 1);
    int h = t >> 5;

    const int HN = H_DIM * N_ST;
    float wr[N_ST], wi[N_ST], Ctr[N_ST], Cti[N_ST];
#pragma unroll
    for (int n = 0; n < N_ST; ++n) {
        wr[n]  = coef[h * N_ST + n];
        wi[n]  = coef[HN + h * N_ST + n];
        Ctr[n] = coef[2 * HN + h * N_ST + n];
        Cti[n] = coef[3 * HN + h * N_ST + n];
    }
    float cw0 = conv_w[h * 4 + 0], cw1 = conv_w[h * 4 + 1];
    float cw2 = conv_w[h * 4 + 2], cw3 = conv_w[h * 4 + 3];
    float cb = conv_b[h];
    float Dh = Dvec[h];

    float* xrow = xz + (size_t)h * L_SEQ + c * CL;
    const float* zrow = xz + (size_t)(H_DIM + h) * L_SEQ + c * CL;

    float4 lk = *(const float4*)(look + (size_t)t * 4);
    float x3 = lk.x, x2 = lk.y, x1 = lk.z;

    const float* st = states + (size_t)t * (N_ST * 2);
    float sr[N_ST], si[N_ST];
#pragma unroll
    for (int n = 0; n < N_ST; ++n) { sr[n] = st[2 * n]; si[n] = st[2 * n + 1]; }

    for (int j = 0; j < CL; j += 4) {
        float4 v = *(const float4*)(xrow + j);
        float4 zv = *(const float4*)(zrow + j);
        float xv[4] = {v.x, v.y, v.z, v.w};
        float zz[4] = {zv.x, zv.y, zv.z, zv.w};
        float out[4];
#pragma unroll
        for (int k = 0; k < 4; ++k) {
            float u = cw0 * x3 + cw1 * x2 + cw2 * x1 + cw3 * xv[k] + cb;
            float xc = u / (1.f + __expf(-u));
            x3 = x2; x2 = x1; x1 = xv[k];
            float accy = 0.f;
#pragma unroll
            for (int n = 0; n < N_ST; ++n) {
                float nr = wr[n] * sr[n] - wi[n] * si[n] + xc;
                float ni = wr[n] * si[n] + wi[n] * sr[n];
                sr[n] = nr; si[n] = ni;
                accy += Ctr[n] * nr - Cti[n] * ni;
            }
            float yv = 2.f * accy + Dh * xc;
            float g = zz[k] / (1.f + __expf(-zz[k]));
            out[k] = yv * g;
        }
        *(float4*)(xrow + j) = make_float4(out[0], out[1], out[2], out[3]);
    }
}

// ============ transpose + split: y f32 [H][L] -> yTh/yTl bf16 [L][H] ============
__global__ __launch_bounds__(256) void transpose_split(const float* __restrict__ y,
                                                       __bf16* __restrict__ th,
                                                       __bf16* __restrict__ tl) {
    __shared__ float tile[64][65];
    const int l0 = blockIdx.x * 64, h0 = blockIdx.y * 64;
    const int tid = threadIdx.x;
    const int r = tid >> 4, c4 = (tid & 15) * 4;
#pragma unroll
    for (int p = 0; p < 4; ++p) {
        float4 v = *(const float4*)(y + (size_t)(h0 + r + p * 16) * L_SEQ + l0 + c4);
        tile[r + p * 16][c4 + 0] = v.x;
        tile[r + p * 16][c4 + 1] = v.y;
        tile[r + p * 16][c4 + 2] = v.z;
        tile[r + p * 16][c4 + 3] = v.w;
    }
    __syncthreads();
    const int l = tid >> 2, hb = (tid & 3) * 16;
    float vals[16];
#pragma unroll
    for (int j = 0; j < 16; ++j) vals[j] = tile[hb + j][l];
    bf16x8 hv0, hv1, lv0, lv1;
#pragma unroll
    for (int j = 0; j < 8; ++j) {
        __bf16 hbv = (__bf16)vals[j];
        hv0[j] = hbv;
        lv0[j] = (__bf16)(vals[j] - (float)hbv);
        __bf16 hbv2 = (__bf16)vals[j + 8];
        hv1[j] = hbv2;
        lv1[j] = (__bf16)(vals[j + 8] - (float)hbv2);
    }
    size_t base = (size_t)(l0 + l) * H_DIM + h0 + hb;
    *(bf16x8*)&th[base] = hv0;
    *(bf16x8*)&th[base + 8] = hv1;
    *(bf16x8*)&tl[base] = lv0;
    *(bf16x8*)&tl[base + 8] = lv1;
}

extern "C" void kernel_launch(void* const* d_in, const int* in_sizes, int n_in,
                              void* d_out, int out_size, void* d_ws, size_t ws_size,
                              hipStream_t stream) {
    const float* hid        = (const float*)d_in[0];
    const float* W_in       = (const float*)d_in[1];
    const float* conv_w     = (const float*)d_in[2];
    const float* conv_b     = (const float*)d_in[3];
    const float* log_dt     = (const float*)d_in[4];
    const float* log_A_real = (const float*)d_in[5];
    const float* A_imag     = (const float*)d_in[6];
    const float* C_re       = (const float*)d_in[7];
    const float* C_im       = (const float*)d_in[8];
    const float* Dv         = (const float*)d_in[9];
    const float* W_out      = (const float*)d_in[10];
    float* out = (float*)d_out;
    float* ws  = (float*)d_ws;

    float* xz      = ws + WS_XZ;
    __bf16* yTh    = (__bf16*)(ws + WS_YTH);
    __bf16* yTl    = (__bf16*)(ws + WS_YTL);
    float* coef    = ws + WS_COEF;
    float* states  = ws + WS_STATES;
    float* look    = ws + WS_LOOK;
    __bf16* Hf     = (__bf16*)(ws + WS_HF);
    __bf16* WiF    = (__bf16*)(ws + WS_WIF);
    __bf16* Woh    = (__bf16*)(ws + WS_WOH);
    __bf16* Wol    = (__bf16*)(ws + WS_WOL);

    coef_kernel<<<(H_DIM * N_ST + 255) / 256, 256, 0, stream>>>(
        log_dt, log_A_real, A_imag, C_re, C_im, coef);

    const int wOct = 2 * H_DIM * DMODEL / 8;   // 524288
    cvt_fuse<0><<<(wOct + 255) / 256, 256, 0, stream>>>(W_in, WiF, wOct);
    cvt_split4<<<(DMODEL * H_DIM / 4 + 255) / 256, 256, 0, stream>>>(W_out, Woh, Wol, DMODEL * H_DIM / 4);

    const int nscan = H_DIM * NC;              // 65536
    const int hOct = L_SEQ * DMODEL / 8;       // 524288
    dim3 gIn(L_SEQ / 256, 2 * H_DIM / 256);    // (16,16) = 256 blocks
    dim3 gOut(DMODEL / 128, L_SEQ / 128);      // (8,32)  = 256 blocks
    dim3 gTr(L_SEQ / 64, H_DIM / 64);          // (64,32)

    for (int b = 0; b < B_SZ; ++b) {
        const float* hid_b = hid + (size_t)b * L_SEQ * DMODEL;
        float* out_b = out + (size_t)b * L_SEQ * DMODEL;

        cvt_fuse<1><<<(hOct + 255) / 256, 256, 0, stream>>>(hid_b, Hf, hOct);
        gemm_f256p<<<gIn, 512, 0, stream>>>(WiF, Hf, xz, 3 * DMODEL, L_SEQ);
        scan_phase1<<<nscan / 256, 256, 0, stream>>>(xz, coef, conv_w, conv_b, states, look);
        scan_phase2<<<(H_DIM + 255) / 256, 256, 0, stream>>>(coef, states);
        scan_phase3<<<nscan / 256, 256, 0, stream>>>(xz, coef, conv_w, conv_b, Dv, states, look);
        transpose_split<<<gTr, 256, 0, stream>>>(xz, yTh, yTl);
        gemm_s128p<<<gOut, 256, 0, stream>>>(yTh, yTl, Woh, Wol, out_b, H_DIM, DMODEL);
    }
}